// Round 1
// baseline (167.309 us; speedup 1.0000x reference)
//
#include <hip/hip_runtime.h>
#include <stdint.h>

#define NNODES 1024
#define NGRAPH 128
#define TOPK   16384
#define EQCAP  4096

// Order-preserving monotone map fp32 -> u32 (larger float => larger key).
__device__ __forceinline__ uint32_t fkey(float x) {
    uint32_t u = __float_as_uint(x);
    return (u & 0x80000000u) ? ~u : (u | 0x80000000u);
}

// ---------------------------------------------------------------------------
// Kernel 1: per graph, sort t[g][:] ascending by key; store sorted values and
// original indices. Also zero the per-graph equal-list counter.
// ---------------------------------------------------------------------------
__global__ __launch_bounds__(NNODES)
void sort_t_kernel(const float* __restrict__ t,
                   float* __restrict__ tval, uint32_t* __restrict__ tidx,
                   uint32_t* __restrict__ eqCnt) {
    const int g = blockIdx.x, tid = threadIdx.x;
    __shared__ uint32_t skey[NNODES];
    __shared__ uint16_t sidx[NNODES];
    skey[tid] = fkey(t[g * NNODES + tid]);
    sidx[tid] = (uint16_t)tid;
    for (int k = 2; k <= NNODES; k <<= 1) {
        for (int j = k >> 1; j > 0; j >>= 1) {
            __syncthreads();
            int partner = tid ^ j;
            if (partner > tid) {
                bool asc = ((tid & k) == 0);
                uint32_t a = skey[tid], b = skey[partner];
                if ((a > b) == asc) {
                    skey[tid] = b; skey[partner] = a;
                    uint16_t ia = sidx[tid]; sidx[tid] = sidx[partner]; sidx[partner] = ia;
                }
            }
        }
    }
    __syncthreads();
    uint32_t idx = sidx[tid];
    tval[g * NNODES + tid] = t[g * NNODES + idx];
    tidx[g * NNODES + tid] = idx;
    if (tid == 0) eqCnt[g] = 0;
}

// ---------------------------------------------------------------------------
// Kernel 2: per graph, binary-search the 32-bit key space for the K-th
// largest product key T (diagonal excluded). R = K - count(key > T).
// count(key > T) is computed with a per-row binary search over sorted t
// (product is monotone in t for fixed s row), block-reduced over 1024 rows.
// ---------------------------------------------------------------------------
__global__ __launch_bounds__(NNODES)
void threshold_kernel(const float* __restrict__ s, const float* __restrict__ t,
                      const float* __restrict__ tval,
                      uint32_t* __restrict__ Tout, uint32_t* __restrict__ Rout) {
    const int g = blockIdx.x, i = threadIdx.x;
    __shared__ float tv[NNODES];
    __shared__ uint32_t wsum[16];
    __shared__ uint32_t sLo, sHi, sCnt;
    tv[i] = tval[g * NNODES + i];
    const float sv = s[g * NNODES + i];
    const bool sneg = (__float_as_uint(sv) >> 31) != 0;
    const uint32_t kdiag = fkey(sv * t[g * NNODES + i]);  // diagonal element (excluded)
    if (i == 0) { sLo = 0u; sHi = 0xFFFFFFFFu; }
    __syncthreads();

    auto cnt_gt = [&](uint32_t T) -> uint32_t {
        // rows with s>=+0: predicate (key>T) true on a suffix of sorted t;
        // rows with s<0 (or -0): true on a prefix.
        int lo = 0, hi = NNODES;
        while (lo < hi) {
            int mid = (lo + hi) >> 1;
            bool pred = fkey(sv * tv[mid]) > T;
            bool goLeft = sneg ? !pred : pred;
            if (goLeft) hi = mid; else lo = mid + 1;
        }
        uint32_t c = sneg ? (uint32_t)lo : (uint32_t)(NNODES - lo);
        if (kdiag > T) c--;                    // remove diagonal if it qualified
        uint32_t r = c;
        for (int off = 32; off; off >>= 1) r += __shfl_down(r, off);
        if ((i & 63) == 0) wsum[i >> 6] = r;
        __syncthreads();
        if (i == 0) {
            uint32_t tot = 0;
            for (int w = 0; w < 16; ++w) tot += wsum[w];
            sCnt = tot;
        }
        __syncthreads();
        return sCnt;
    };

    // find minimal T with cnt_gt(T) < K  (== the K-th largest key)
    for (int it = 0; it < 32; ++it) {
        uint32_t lo = sLo, hi = sHi;
        uint32_t mid = lo + ((hi - lo) >> 1);
        uint32_t c = cnt_gt(mid);
        if (i == 0 && lo < hi) {
            if (c < TOPK) sHi = mid; else sLo = mid + 1;
        }
        __syncthreads();
    }
    uint32_t T = sLo;
    uint32_t c = cnt_gt(T);
    if (i == 0) { Tout[g] = T; Rout[g] = TOPK - c; }
}

// ---------------------------------------------------------------------------
// Kernel 3: collect flat indices of elements with key == T (excluding the
// diagonal) into a small per-graph list.
// ---------------------------------------------------------------------------
__global__ __launch_bounds__(NNODES)
void collect_kernel(const float* __restrict__ s,
                    const float* __restrict__ tval, const uint32_t* __restrict__ tidx,
                    const uint32_t* __restrict__ Tin,
                    uint32_t* __restrict__ eqCnt, uint32_t* __restrict__ eqIdx) {
    const int g = blockIdx.x, i = threadIdx.x;
    const uint32_t T = Tin[g];
    const float sv = s[g * NNODES + i];
    const bool sneg = (__float_as_uint(sv) >> 31) != 0;
    const float* tv = tval + g * NNODES;

    auto bound = [&](bool ge) -> int {
        int lo = 0, hi = NNODES;
        while (lo < hi) {
            int mid = (lo + hi) >> 1;
            uint32_t k = fkey(sv * tv[mid]);
            bool pred = ge ? (k >= T) : (k > T);
            bool goLeft = sneg ? !pred : pred;
            if (goLeft) hi = mid; else lo = mid + 1;
        }
        return lo;
    };
    int e0, e1;
    if (!sneg) { e0 = bound(true);  e1 = bound(false); }   // equals = [ge_start, gt_start)
    else       { e0 = bound(false); e1 = bound(true);  }   // equals = [gt_end, ge_end)
    for (int p = e0; p < e1; ++p) {
        uint32_t j = tidx[g * NNODES + p];
        if ((int)j == i) continue;                          // diagonal excluded
        uint32_t slot = atomicAdd(&eqCnt[g], 1u);
        if (slot < EQCAP) eqIdx[g * EQCAP + slot] = (uint32_t)(i * NNODES) + j;
    }
}

// ---------------------------------------------------------------------------
// Kernel 4: full output write: out = (key > T) && (i != j). One block per
// output row; float4 stores (1 KiB per wave instruction).
// ---------------------------------------------------------------------------
__global__ __launch_bounds__(256)
void write_kernel(const float* __restrict__ s, const float* __restrict__ t,
                  const uint32_t* __restrict__ Tin, float* __restrict__ out) {
    const int b = blockIdx.x;           // g*1024 + i
    const int g = b >> 10, i = b & 1023;
    const uint32_t T = Tin[g];
    const float sv = s[(size_t)g * NNODES + i];
    const float4 tv = ((const float4*)(t + (size_t)g * NNODES))[threadIdx.x];
    const int j0 = threadIdx.x * 4;
    float4 r;
    r.x = (fkey(sv * tv.x) > T && (j0 + 0) != i) ? 1.0f : 0.0f;
    r.y = (fkey(sv * tv.y) > T && (j0 + 1) != i) ? 1.0f : 0.0f;
    r.z = (fkey(sv * tv.z) > T && (j0 + 2) != i) ? 1.0f : 0.0f;
    r.w = (fkey(sv * tv.w) > T && (j0 + 3) != i) ? 1.0f : 0.0f;
    ((float4*)(out + (size_t)g * NNODES * NNODES + (size_t)i * NNODES))[threadIdx.x] = r;
}

// ---------------------------------------------------------------------------
// Kernel 5: among equals, set the R smallest flat indices to 1 (matches
// jax.lax.top_k tie-breaking: lower index preferred).
// ---------------------------------------------------------------------------
__global__ __launch_bounds__(256)
void scatter_kernel(const uint32_t* __restrict__ eqCnt, const uint32_t* __restrict__ eqIdx,
                    const uint32_t* __restrict__ Rin, float* __restrict__ out) {
    const int g = blockIdx.x;
    uint32_t E = eqCnt[g]; if (E > EQCAP) E = EQCAP;
    const uint32_t R = Rin[g];
    __shared__ uint32_t se[EQCAP];
    for (uint32_t p = threadIdx.x; p < E; p += blockDim.x) se[p] = eqIdx[g * EQCAP + p];
    __syncthreads();
    for (uint32_t p = threadIdx.x; p < E; p += blockDim.x) {
        uint32_t v = se[p], rank = 0;
        for (uint32_t q = 0; q < E; ++q) rank += (se[q] < v) ? 1u : 0u;
        if (rank < R) out[(size_t)g * NNODES * NNODES + v] = 1.0f;
    }
}

extern "C" void kernel_launch(void* const* d_in, const int* in_sizes, int n_in,
                              void* d_out, int out_size, void* d_ws, size_t ws_size,
                              hipStream_t stream) {
    // inputs: x (unused), emb_s [G,N,1], emb_t [G,1,N] -- all float32
    const float* s = (const float*)d_in[1];
    const float* t = (const float*)d_in[2];
    float* out = (float*)d_out;

    char* ws = (char*)d_ws;
    float*    tval  = (float*)ws;    ws += (size_t)NGRAPH * NNODES * 4;
    uint32_t* tidx  = (uint32_t*)ws; ws += (size_t)NGRAPH * NNODES * 4;
    uint32_t* Tbuf  = (uint32_t*)ws; ws += (size_t)NGRAPH * 4;
    uint32_t* Rbuf  = (uint32_t*)ws; ws += (size_t)NGRAPH * 4;
    uint32_t* eqCnt = (uint32_t*)ws; ws += (size_t)NGRAPH * 4;
    uint32_t* eqIdx = (uint32_t*)ws; ws += (size_t)NGRAPH * EQCAP * 4;

    sort_t_kernel<<<NGRAPH, NNODES, 0, stream>>>(t, tval, tidx, eqCnt);
    threshold_kernel<<<NGRAPH, NNODES, 0, stream>>>(s, t, tval, Tbuf, Rbuf);
    collect_kernel<<<NGRAPH, NNODES, 0, stream>>>(s, tval, tidx, Tbuf, eqCnt, eqIdx);
    write_kernel<<<NGRAPH * NNODES, 256, 0, stream>>>(s, t, Tbuf, out);
    scatter_kernel<<<NGRAPH, 256, 0, stream>>>(eqCnt, eqIdx, Rbuf, out);
}